// Round 4
// baseline (10.327 us; speedup 1.0000x reference)
//
#include <hip/hip_runtime.h>

// Analytic closed form of the 4-qubit circuit (AngleEmbedding RX + 2
// BasicEntanglerLayers with CNOT ring), Heisenberg-picture Pauli propagation.
// a_q = x_q + w0_q (merged), b_q = w1_q:
//   <Z0> = ca0*(U1*A + U2*B) + sa0*(U3*B + U4*A)
//   <Z1> = ca3*(V1*ca0*ca2 + V2*sa0*sa2)
//   <Z2> = P1*A + P2*B
//   A = ca1*ca3, B = sa1*sa3, U1=cb1cb2cb3, U2=sb1sb2cb3, U3=cb1cb2sb3,
//   U4=sb1sb2sb3, V1=cb0cb1, V2=sb0sb1, P1=cb0cb1cb2, P2=cb0sb1sb2.
// Verified vs direct statevector sim at 8 corner/superposition points.
//
// 4 samples per thread: amortizes the batch-uniform trig (qw[4..7]) 4x and
// vectorizes the output as 3x float4 per thread (12 contiguous floats).

__device__ __forceinline__ void zcalc(
        float4 x, float w0, float w1, float w2, float w3,
        float U1, float U2, float U3, float U4,
        float V1, float V2, float P1, float P2,
        float* z) {
    float sa0, ca0, sa1, ca1, sa2, ca2, sa3, ca3;
    __sincosf(x.x + w0, &sa0, &ca0);
    __sincosf(x.y + w1, &sa1, &ca1);
    __sincosf(x.z + w2, &sa2, &ca2);
    __sincosf(x.w + w3, &sa3, &ca3);
    const float A = ca1 * ca3;
    const float B = sa1 * sa3;
    z[0] = fmaf(sa0, fmaf(U3, B, U4 * A), ca0 * fmaf(U1, A, U2 * B));
    z[1] = ca3 * fmaf(V1, ca0 * ca2, V2 * (sa0 * sa2));
    z[2] = fmaf(P1, A, P2 * B);
}

__global__ __launch_bounds__(256) void qexp_kernel(
        const float4* __restrict__ in4,    // one float4 per sample
        const float* __restrict__ qw,      // (2,4) f32
        float4* __restrict__ out4,         // 3 float4 per 4 samples
        float* __restrict__ out_scalar,
        int batch) {
    const int t = blockIdx.x * blockDim.x + threadIdx.x;
    const int base = t * 4;
    if (base >= batch) return;

    // Batch-uniform layer-1 coefficients (amortized over 4 samples).
    float sb0, cb0, sb1, cb1, sb2, cb2, sb3, cb3;
    __sincosf(qw[4], &sb0, &cb0);
    __sincosf(qw[5], &sb1, &cb1);
    __sincosf(qw[6], &sb2, &cb2);
    __sincosf(qw[7], &sb3, &cb3);
    const float Pu = cb1 * cb2, Qu = sb1 * sb2;
    const float U1 = Pu * cb3, U2 = Qu * cb3, U3 = Pu * sb3, U4 = Qu * sb3;
    const float V1 = cb0 * cb1, V2 = sb0 * sb1;
    const float P1 = cb0 * Pu,  P2 = cb0 * Qu;
    const float w0 = qw[0], w1 = qw[1], w2 = qw[2], w3 = qw[3];

    if (base + 3 < batch) {
        float z[12];
#pragma unroll
        for (int k = 0; k < 4; ++k) {
            zcalc(in4[base + k], w0, w1, w2, w3,
                  U1, U2, U3, U4, V1, V2, P1, P2, z + 3 * k);
        }
        out4[3 * t + 0] = make_float4(z[0], z[1], z[2],  z[3]);
        out4[3 * t + 1] = make_float4(z[4], z[5], z[6],  z[7]);
        out4[3 * t + 2] = make_float4(z[8], z[9], z[10], z[11]);
    } else {
        // Tail (batch not divisible by 4): scalar stores.
        for (int k = 0; k < 4 && base + k < batch; ++k) {
            float z[3];
            zcalc(in4[base + k], w0, w1, w2, w3,
                  U1, U2, U3, U4, V1, V2, P1, P2, z);
            float* o = out_scalar + (size_t)(base + k) * 3;
            o[0] = z[0]; o[1] = z[1]; o[2] = z[2];
        }
    }
}

extern "C" void kernel_launch(void* const* d_in, const int* in_sizes, int n_in,
                              void* d_out, int out_size, void* d_ws, size_t ws_size,
                              hipStream_t stream) {
    const float4* inputs = (const float4*)d_in[0];  // (B,4) f32
    const float* qw      = (const float*)d_in[1];   // (2,4) f32
    const int batch = in_sizes[0] / 4;

    const int nthreads = (batch + 3) / 4;
    const int block = 256;
    const int grid = (nthreads + block - 1) / block;
    qexp_kernel<<<grid, block, 0, stream>>>(inputs, qw, (float4*)d_out,
                                            (float*)d_out, batch);
}